// Round 6
// baseline (137.001 us; speedup 1.0000x reference)
//
#include <hip/hip_runtime.h>
#include <math.h>

#define CCH 4096
#define SP 891
#define SPADE 896
#define NSL 32768

typedef __attribute__((ext_vector_type(8))) short short8;
typedef __attribute__((ext_vector_type(4))) float f32x4;

__device__ __forceinline__ unsigned int pack_bf2(float a, float b) {
  unsigned int ua = __builtin_bit_cast(unsigned int, a);
  unsigned int ub = __builtin_bit_cast(unsigned int, b);
  ua = (ua + 0x7fffu + ((ua >> 16) & 1u)) >> 16;
  ub = (ub + 0x7fffu + ((ub >> 16) & 1u)) >> 16;
  return ua | (ub << 16);
}

// ---------- setup: members + rowSid + cnt/off (80 blocks x 64) ----------
__global__ void k_setup(const int* __restrict__ im0, const int* __restrict__ im1,
                        int* cnt0, int* off0, int* cnt1, int* off1,
                        int* mem0, int* mem1, int* rs0, int* rs1) {
  int cb = blockIdx.x;
  int level = (cb >= 64) ? 1 : 0;
  int c = level ? cb - 64 : cb;
  const int* im = level ? im1 : im0;
  int* members = level ? mem1 : mem0;
  int* rs = level ? rs1 : rs0;
  int lane = threadIdx.x;  // 64
  int lt = 0;
  for (int ch = lane; ch < CCH; ch += 64) lt += (im[ch] < c) ? 1 : 0;
  for (int o = 32; o; o >>= 1) lt += __shfl_xor(lt, o, 64);
  int base = lt;
  int cnt = 0;
  for (int chunk = 0; chunk < CCH; chunk += 64) {
    int ch = chunk + lane;
    bool m = (im[ch] == c);
    unsigned long long mk = __ballot(m);
    int pos = __popcll(mk & ((1ull << lane) - 1ull));
    if (m) members[base + cnt + pos] = ch;
    cnt += __popcll(mk);
  }
  int n = cnt;
  if (lane == 0) {
    if (level) { cnt1[c] = n; off1[c] = base; }
    else       { cnt0[c] = n; off0[c] = base; }
  }
  __syncthreads();
  for (int r = lane; r < n; r += 64) {
    #pragma unroll
    for (int q = 0; q < 8; q++) {
      int p = 8 * r + q;
      int b = p / n, j = p - b * n;
      rs[(size_t)(base + r) * 8 + q] = b * CCH + members[base + j];
    }
  }
}

// ---------- convert X -> bf16 padded + fp32 slice norms ----------
__global__ __launch_bounds__(256) void k_convert(const float* __restrict__ X,
    unsigned int* __restrict__ Xbf32, float* __restrict__ sn2) {
  int w = threadIdx.x >> 6, l = threadIdx.x & 63;
  for (int sid = blockIdx.x * 4 + w; sid < NSL; sid += gridDim.x * 4) {
    const float* src = X + (size_t)sid * SP;
    unsigned int* dst = Xbf32 + (size_t)sid * (SPADE / 2);
    float s2 = 0.f;
    #pragma unroll
    for (int p = 0; p < 7; p++) {
      int e = p * 128 + l * 2;
      float v0 = (e < SP) ? src[e] : 0.f;
      float v1 = (e + 1 < SP) ? src[e + 1] : 0.f;
      s2 += v0 * v0 + v1 * v1;
      dst[p * 64 + l] = pack_bf2(v0, v1);
    }
    for (int o = 32; o; o >>= 1) s2 += __shfl_xor(s2, o, 64);
    if (l == 0) sn2[sid] = s2;
  }
}

// ---------- register-direct MFMA GEMM, both levels, no LDS, no barriers ----------
__global__ __launch_bounds__(256) void k_gemm_all(
    const unsigned short* __restrict__ Xbf,
    const int* __restrict__ rs0, const int* __restrict__ rs1,
    const int* __restrict__ off0, const int* __restrict__ off1,
    float* __restrict__ P8_0, float* __restrict__ P8_1) {
  const int q = blockIdx.y, tid = threadIdx.x;
  const int l = tid & 63, w = tid >> 6;
  const int lrow = l & 15, lk = (l >> 4) * 8;
  if (blockIdx.x < 128) {
    // L0: TM=32, N=64. waves: wm=w&1 (rows), wn=w>>1 (col pair)
    const int wm = w & 1, wn = w >> 1;
    const int rowA = blockIdx.x * 32 + wm * 16 + lrow;
    const size_t sa = (size_t)rs0[(size_t)rowA * 8 + q] * SPADE + lk;
    const int col0 = wn * 32 + lrow, col1 = col0 + 16;
    const size_t sb0 = (size_t)rs0[(size_t)off0[col0] * 8 + q] * SPADE + lk;
    const size_t sb1 = (size_t)rs0[(size_t)off0[col1] * 8 + q] * SPADE + lk;
    f32x4 acc0 = {0.f, 0.f, 0.f, 0.f}, acc1 = {0.f, 0.f, 0.f, 0.f};
    #pragma unroll 4
    for (int kc = 0; kc < 28; kc++) {
      const int k = kc * 32;
      short8 a  = *(const short8*)(Xbf + sa + k);
      short8 b0 = *(const short8*)(Xbf + sb0 + k);
      short8 b1 = *(const short8*)(Xbf + sb1 + k);
      acc0 = __builtin_amdgcn_mfma_f32_16x16x32_bf16(a, b0, acc0, 0, 0, 0);
      acc1 = __builtin_amdgcn_mfma_f32_16x16x32_bf16(a, b1, acc1, 0, 0, 0);
    }
    #pragma unroll
    for (int r = 0; r < 4; r++) {
      int row = blockIdx.x * 32 + wm * 16 + (l >> 4) * 4 + r;
      float* dst = P8_0 + ((size_t)q * CCH + row) * 64;
      dst[wn * 32 + lrow] = acc0[r];
      dst[wn * 32 + 16 + lrow] = acc1[r];
    }
  } else {
    // L1: TM=64, N=16. 4 waves = 4 row strips
    const int bx = blockIdx.x - 128;
    const int rowA = bx * 64 + w * 16 + lrow;
    const size_t sa = (size_t)rs1[(size_t)rowA * 8 + q] * SPADE + lk;
    const size_t sb = (size_t)rs1[(size_t)off1[lrow] * 8 + q] * SPADE + lk;
    f32x4 acc = {0.f, 0.f, 0.f, 0.f};
    #pragma unroll 4
    for (int kc = 0; kc < 28; kc++) {
      const int k = kc * 32;
      short8 a = *(const short8*)(Xbf + sa + k);
      short8 b = *(const short8*)(Xbf + sb + k);
      acc = __builtin_amdgcn_mfma_f32_16x16x32_bf16(a, b, acc, 0, 0, 0);
    }
    #pragma unroll
    for (int r = 0; r < 4; r++) {
      int row = bx * 64 + w * 16 + (l >> 4) * 4 + r;
      P8_1[((size_t)q * CCH + row) * 16 + lrow] = acc[r];
    }
  }
}

// ---------- per-cluster epilogue, both levels in one dispatch ----------
template<int K>
__device__ __forceinline__ void fin_body(const float* __restrict__ P8,
    const float* __restrict__ sn2, const int* __restrict__ rs,
    const int* __restrict__ cnt, const int* __restrict__ off,
    double* __restrict__ clLoss, int c) {
  __shared__ float pcc[4096];
  __shared__ float red[256];
  __shared__ double redd[256];
  __shared__ float s_conc;
  const int n = cnt[c], base = off[c];
  const int tid = threadIdx.x;
  float rn0 = 0.f;
  #pragma unroll
  for (int qq = 0; qq < 8; qq++) rn0 += sn2[rs[(size_t)base * 8 + qq]];
  float t = 0.f;
  for (int r = tid; r < n; r += 256) {
    float pd = 0.f, rn = 0.f;
    #pragma unroll
    for (int qq = 0; qq < 8; qq++) {
      pd += P8[((size_t)qq * CCH + base + r) * K + c];
      rn += sn2[rs[(size_t)(base + r) * 8 + qq]];
    }
    pcc[r] = pd;
    if (r > 0) {
      float d2 = rn - 2.f * pd + rn0;
      t += (d2 > 0.f) ? sqrtf(d2) : 0.f;
    }
  }
  red[tid] = t; __syncthreads();
  for (int o = 128; o; o >>= 1) { if (tid < o) red[tid] += red[tid + o]; __syncthreads(); }
  if (tid == 0) s_conc = red[0] / ((float)n * logf((float)n + 10.f));
  __syncthreads();
  const float invc = 1.f / s_conc;
  const int wv = tid >> 6, lane = tid & 63;
  const int sub = (K == 64) ? 0 : (lane >> 4);
  const int cc = lane & (K - 1);
  constexpr int RPI = (K == 64) ? 4 : 16;
  double acc = 0.0;
  for (int r = wv * (RPI / 4) + sub; r < n; r += RPI) {
    float s = 0.f;
    #pragma unroll
    for (int qq = 0; qq < 8; qq++) s += P8[((size_t)qq * CCH + base + r) * K + cc];
    float lg = s * invc;
    float m = lg;
    #pragma unroll
    for (int o = K / 2; o; o >>= 1) m = fmaxf(m, __shfl_xor(m, o, K));
    float e = expf(lg - m);
    float se = e;
    #pragma unroll
    for (int o = K / 2; o; o >>= 1) se += __shfl_xor(se, o, K);
    if (cc == 0) acc += (double)(m + logf(se)) - (double)(pcc[r] * invc);
  }
  redd[tid] = acc; __syncthreads();
  for (int o = 128; o; o >>= 1) { if (tid < o) redd[tid] += redd[tid + o]; __syncthreads(); }
  if (tid == 0) clLoss[c] = redd[0] / (double)n;
}

__global__ __launch_bounds__(256) void k_fin_all(const float* __restrict__ P8_0,
    const float* __restrict__ P8_1, const float* __restrict__ sn2,
    const int* __restrict__ rs0, const int* __restrict__ rs1,
    const int* __restrict__ cnt0, const int* __restrict__ off0,
    const int* __restrict__ cnt1, const int* __restrict__ off1,
    double* __restrict__ cl0, double* __restrict__ cl1) {
  if (blockIdx.x < 64) fin_body<64>(P8_0, sn2, rs0, cnt0, off0, cl0, blockIdx.x);
  else                 fin_body<16>(P8_1, sn2, rs1, cnt1, off1, cl1, blockIdx.x - 64);
}

// ---------- final scalars ----------
__global__ void k_final(const double* __restrict__ cl0, const double* __restrict__ cl1,
                        float* __restrict__ out) {
  if (threadIdx.x == 0) {
    double s0 = 0.0, s1 = 0.0;
    for (int i = 0; i < 64; i++) s0 += cl0[i];
    for (int i = 0; i < 16; i++) s1 += cl1[i];
    out[0] = (float)(s0 / 4096.0);
    out[1] = (float)(s1 / 8192.0);
  }
}

extern "C" void kernel_launch(void* const* d_in, const int* in_sizes, int n_in,
                              void* d_out, int out_size, void* d_ws, size_t ws_size,
                              hipStream_t stream) {
  const float* X = (const float*)d_in[0];
  const int* im0 = (const int*)d_in[1];
  const int* im1 = (const int*)d_in[2];
  float* out = (float*)d_out;

  char* w = (char*)d_ws;
  auto alloc = [&](size_t bytes) -> char* {
    char* p = w; w += (bytes + 255) & ~(size_t)255; return p;
  };
  int*    cnt0  = (int*)alloc(64 * 4);
  int*    off0  = (int*)alloc(64 * 4);
  int*    cnt1  = (int*)alloc(16 * 4);
  int*    off1  = (int*)alloc(16 * 4);
  int*    mem0  = (int*)alloc((size_t)CCH * 4);
  int*    mem1  = (int*)alloc((size_t)CCH * 4);
  int*    rs0   = (int*)alloc((size_t)CCH * 8 * 4);
  int*    rs1   = (int*)alloc((size_t)CCH * 8 * 4);
  float*  sn2   = (float*)alloc((size_t)NSL * 4);
  unsigned short* Xbf = (unsigned short*)alloc((size_t)NSL * SPADE * 2);
  float*  P8_0  = (float*)alloc((size_t)8 * CCH * 64 * 4);
  float*  P8_1  = (float*)alloc((size_t)8 * CCH * 16 * 4);
  double* cl0   = (double*)alloc(64 * 8);
  double* cl1   = (double*)alloc(16 * 8);

  k_convert<<<2048, 256, 0, stream>>>(X, (unsigned int*)Xbf, sn2);
  k_setup<<<80, 64, 0, stream>>>(im0, im1, cnt0, off0, cnt1, off1, mem0, mem1, rs0, rs1);
  k_gemm_all<<<dim3(192, 8), 256, 0, stream>>>(Xbf, rs0, rs1, off0, off1, P8_0, P8_1);
  k_fin_all<<<80, 256, 0, stream>>>(P8_0, P8_1, sn2, rs0, rs1, cnt0, off0, cnt1, off1, cl0, cl1);
  k_final<<<1, 64, 0, stream>>>(cl0, cl1, out);
}

// Round 7
// 114.670 us; speedup vs baseline: 1.1947x; 1.1947x over previous
//
#include <hip/hip_runtime.h>
#include <math.h>

#define CCH 4096
#define SP 891

typedef __attribute__((ext_vector_type(8))) short short8;
typedef __attribute__((ext_vector_type(4))) float f32x4;

__device__ __forceinline__ unsigned int pack_bf2(float a, float b) {
  unsigned int ua = __builtin_bit_cast(unsigned int, a);
  unsigned int ub = __builtin_bit_cast(unsigned int, b);
  ua = (ua + 0x7fffu + ((ua >> 16) & 1u)) >> 16;
  ub = (ub + 0x7fffu + ((ub >> 16) & 1u)) >> 16;
  return ua | (ub << 16);
}

// ---------- setup: members + rowSid + cnt/off (80 blocks x 64) ----------
__global__ void k_setup(const int* __restrict__ im0, const int* __restrict__ im1,
                        int* cnt0, int* off0, int* cnt1, int* off1,
                        int* mem0, int* mem1, int* rs0, int* rs1) {
  int cb = blockIdx.x;
  int level = (cb >= 64) ? 1 : 0;
  int c = level ? cb - 64 : cb;
  const int* im = level ? im1 : im0;
  int* members = level ? mem1 : mem0;
  int* rs = level ? rs1 : rs0;
  int lane = threadIdx.x;  // 64
  int lt = 0;
  for (int ch = lane; ch < CCH; ch += 64) lt += (im[ch] < c) ? 1 : 0;
  for (int o = 32; o; o >>= 1) lt += __shfl_xor(lt, o, 64);
  int base = lt;
  int cnt = 0;
  for (int chunk = 0; chunk < CCH; chunk += 64) {
    int ch = chunk + lane;
    bool m = (im[ch] == c);
    unsigned long long mk = __ballot(m);
    int pos = __popcll(mk & ((1ull << lane) - 1ull));
    if (m) members[base + cnt + pos] = ch;
    cnt += __popcll(mk);
  }
  int n = cnt;
  if (lane == 0) {
    if (level) { cnt1[c] = n; off1[c] = base; }
    else       { cnt0[c] = n; off0[c] = base; }
  }
  __syncthreads();
  for (int r = lane; r < n; r += 64) {
    #pragma unroll
    for (int q = 0; q < 8; q++) {
      int p = 8 * r + q;
      int b = p / n, j = p - b * n;
      rs[(size_t)(base + r) * 8 + q] = b * CCH + members[base + j];
    }
  }
}

// ---------- pack rep slices into fragment-major bf16 tables ----------
// Bfrag0[((q*4+ct)*28+kc)*64 + l], Bfrag1[(q*28+kc)*64 + l]; lane l = (row=l&15, hi=l>>4)
__global__ void k_brep(const float* __restrict__ X,
    const int* __restrict__ off0, const int* __restrict__ off1,
    const int* __restrict__ rs0, const int* __restrict__ rs1,
    uint4* __restrict__ Bfrag0, uint4* __restrict__ Bfrag1) {
  int gid = blockIdx.x * 4 + (threadIdx.x >> 6);  // 0..39
  int l = threadIdx.x & 63;
  int lrow = l & 15, hi = l >> 4;
  int level = (gid >= 32) ? 1 : 0;
  int q = level ? (gid - 32) : (gid >> 2);
  int ct = level ? 0 : (gid & 3);
  int cc = ct * 16 + lrow;
  int base = level ? off1[cc] : off0[cc];
  int sid = (level ? rs1 : rs0)[(size_t)base * 8 + q];
  const float* ap = X + (size_t)sid * SP + hi * 8;
  uint4* dst = (level ? Bfrag1 + (size_t)(q * 28) * 64
                      : Bfrag0 + (size_t)((q * 4 + ct) * 28) * 64) + l;
  #pragma unroll 3
  for (int kc = 0; kc < 27; kc++) {
    float4 fa0 = *(const float4*)(ap + kc * 32);
    float4 fa1 = *(const float4*)(ap + kc * 32 + 4);
    uint4 ua;
    ua.x = pack_bf2(fa0.x, fa0.y); ua.y = pack_bf2(fa0.z, fa0.w);
    ua.z = pack_bf2(fa1.x, fa1.y); ua.w = pack_bf2(fa1.z, fa1.w);
    dst[kc * 64] = ua;
  }
  {  // kc = 27: k = 864 + hi*8 + j, valid while < 891
    float4 fa0, fa1;
    if (hi == 3) {
      fa0 = make_float4(ap[864], ap[865], ap[866], 0.f);
      fa1 = make_float4(0.f, 0.f, 0.f, 0.f);
    } else {
      fa0 = *(const float4*)(ap + 864);
      fa1 = *(const float4*)(ap + 868);
    }
    uint4 ua;
    ua.x = pack_bf2(fa0.x, fa0.y); ua.y = pack_bf2(fa0.z, fa0.w);
    ua.z = pack_bf2(fa1.x, fa1.y); ua.w = pack_bf2(fa1.z, fa1.w);
    dst[27 * 64] = ua;
  }
}

// ---------- register-direct MFMA GEMM, fp32 A with in-reg pack, fused sn2 ----------
__global__ __launch_bounds__(256) void k_gemm_all(const float* __restrict__ X,
    const int* __restrict__ rs0, const int* __restrict__ rs1,
    const uint4* __restrict__ Bfrag0, const uint4* __restrict__ Bfrag1,
    float* __restrict__ P8_0, float* __restrict__ P8_1, float* __restrict__ sn2) {
  const int q = blockIdx.y, tid = threadIdx.x;
  const int l = tid & 63, w = tid >> 6;
  const int lrow = l & 15, hi = l >> 4;
  if (blockIdx.x < 128) {
    // L0: TM=32 (2 row tiles), N=64 (2 waves x 2 col strips of 32)
    const int wm = w & 1, wn = w >> 1;
    const int rowTile = blockIdx.x * 2 + wm;
    const int sid = rs0[(size_t)(rowTile * 16 + lrow) * 8 + q];
    const float* ap = X + (size_t)sid * SP + hi * 8;
    const uint4* bq0 = Bfrag0 + (size_t)((q * 4 + wn * 2) * 28) * 64 + l;
    const uint4* bq1 = Bfrag0 + (size_t)((q * 4 + wn * 2 + 1) * 28) * 64 + l;
    f32x4 acc0 = {0.f, 0.f, 0.f, 0.f}, acc1 = {0.f, 0.f, 0.f, 0.f};
    float s2 = 0.f;
    #pragma unroll 3
    for (int kc = 0; kc < 27; kc++) {
      float4 fa0 = *(const float4*)(ap + kc * 32);
      float4 fa1 = *(const float4*)(ap + kc * 32 + 4);
      uint4 ub0 = bq0[kc * 64];
      uint4 ub1 = bq1[kc * 64];
      uint4 ua;
      ua.x = pack_bf2(fa0.x, fa0.y); ua.y = pack_bf2(fa0.z, fa0.w);
      ua.z = pack_bf2(fa1.x, fa1.y); ua.w = pack_bf2(fa1.z, fa1.w);
      s2 += fa0.x * fa0.x + fa0.y * fa0.y + fa0.z * fa0.z + fa0.w * fa0.w
          + fa1.x * fa1.x + fa1.y * fa1.y + fa1.z * fa1.z + fa1.w * fa1.w;
      short8 a = __builtin_bit_cast(short8, ua);
      acc0 = __builtin_amdgcn_mfma_f32_16x16x32_bf16(a, __builtin_bit_cast(short8, ub0), acc0, 0, 0, 0);
      acc1 = __builtin_amdgcn_mfma_f32_16x16x32_bf16(a, __builtin_bit_cast(short8, ub1), acc1, 0, 0, 0);
    }
    {  // kc = 27 masked
      float4 fa0, fa1;
      if (hi == 3) {
        fa0 = make_float4(ap[864], ap[865], ap[866], 0.f);
        fa1 = make_float4(0.f, 0.f, 0.f, 0.f);
      } else {
        fa0 = *(const float4*)(ap + 864);
        fa1 = *(const float4*)(ap + 868);
      }
      uint4 ub0 = bq0[27 * 64];
      uint4 ub1 = bq1[27 * 64];
      uint4 ua;
      ua.x = pack_bf2(fa0.x, fa0.y); ua.y = pack_bf2(fa0.z, fa0.w);
      ua.z = pack_bf2(fa1.x, fa1.y); ua.w = pack_bf2(fa1.z, fa1.w);
      s2 += fa0.x * fa0.x + fa0.y * fa0.y + fa0.z * fa0.z + fa0.w * fa0.w
          + fa1.x * fa1.x + fa1.y * fa1.y + fa1.z * fa1.z + fa1.w * fa1.w;
      short8 a = __builtin_bit_cast(short8, ua);
      acc0 = __builtin_amdgcn_mfma_f32_16x16x32_bf16(a, __builtin_bit_cast(short8, ub0), acc0, 0, 0, 0);
      acc1 = __builtin_amdgcn_mfma_f32_16x16x32_bf16(a, __builtin_bit_cast(short8, ub1), acc1, 0, 0, 0);
    }
    #pragma unroll
    for (int r = 0; r < 4; r++) {
      int row = rowTile * 16 + hi * 4 + r;
      float* dst = P8_0 + ((size_t)q * CCH + row) * 64;
      dst[wn * 32 + lrow] = acc0[r];
      dst[wn * 32 + 16 + lrow] = acc1[r];
    }
    s2 += __shfl_xor(s2, 16, 64);
    s2 += __shfl_xor(s2, 32, 64);
    if (wn == 0 && hi == 0) sn2[sid] = s2;
  } else {
    // L1: TM=64 (4 waves = 4 row tiles), N=16
    const int bx = blockIdx.x - 128;
    const int rowTile = bx * 4 + w;
    const int sid = rs1[(size_t)(rowTile * 16 + lrow) * 8 + q];
    const float* ap = X + (size_t)sid * SP + hi * 8;
    const uint4* bq = Bfrag1 + (size_t)(q * 28) * 64 + l;
    f32x4 acc = {0.f, 0.f, 0.f, 0.f};
    #pragma unroll 3
    for (int kc = 0; kc < 27; kc++) {
      float4 fa0 = *(const float4*)(ap + kc * 32);
      float4 fa1 = *(const float4*)(ap + kc * 32 + 4);
      uint4 ub = bq[kc * 64];
      uint4 ua;
      ua.x = pack_bf2(fa0.x, fa0.y); ua.y = pack_bf2(fa0.z, fa0.w);
      ua.z = pack_bf2(fa1.x, fa1.y); ua.w = pack_bf2(fa1.z, fa1.w);
      acc = __builtin_amdgcn_mfma_f32_16x16x32_bf16(
          __builtin_bit_cast(short8, ua), __builtin_bit_cast(short8, ub), acc, 0, 0, 0);
    }
    {
      float4 fa0, fa1;
      if (hi == 3) {
        fa0 = make_float4(ap[864], ap[865], ap[866], 0.f);
        fa1 = make_float4(0.f, 0.f, 0.f, 0.f);
      } else {
        fa0 = *(const float4*)(ap + 864);
        fa1 = *(const float4*)(ap + 868);
      }
      uint4 ub = bq[27 * 64];
      uint4 ua;
      ua.x = pack_bf2(fa0.x, fa0.y); ua.y = pack_bf2(fa0.z, fa0.w);
      ua.z = pack_bf2(fa1.x, fa1.y); ua.w = pack_bf2(fa1.z, fa1.w);
      acc = __builtin_amdgcn_mfma_f32_16x16x32_bf16(
          __builtin_bit_cast(short8, ua), __builtin_bit_cast(short8, ub), acc, 0, 0, 0);
    }
    #pragma unroll
    for (int r = 0; r < 4; r++) {
      int row = rowTile * 16 + hi * 4 + r;
      P8_1[((size_t)q * CCH + row) * 16 + lrow] = acc[r];
    }
  }
}

// ---------- per-cluster epilogue, both levels in one dispatch ----------
template<int K>
__device__ __forceinline__ void fin_body(const float* __restrict__ P8,
    const float* __restrict__ sn2, const int* __restrict__ rs,
    const int* __restrict__ cnt, const int* __restrict__ off,
    double* __restrict__ clLoss, int c) {
  __shared__ float pcc[4096];
  __shared__ float red[256];
  __shared__ double redd[256];
  __shared__ float s_conc;
  const int n = cnt[c], base = off[c];
  const int tid = threadIdx.x;
  float rn0 = 0.f;
  #pragma unroll
  for (int qq = 0; qq < 8; qq++) rn0 += sn2[rs[(size_t)base * 8 + qq]];
  float t = 0.f;
  for (int r = tid; r < n; r += 256) {
    float pd = 0.f, rn = 0.f;
    #pragma unroll
    for (int qq = 0; qq < 8; qq++) {
      pd += P8[((size_t)qq * CCH + base + r) * K + c];
      rn += sn2[rs[(size_t)(base + r) * 8 + qq]];
    }
    pcc[r] = pd;
    if (r > 0) {
      float d2 = rn - 2.f * pd + rn0;
      t += (d2 > 0.f) ? sqrtf(d2) : 0.f;
    }
  }
  red[tid] = t; __syncthreads();
  for (int o = 128; o; o >>= 1) { if (tid < o) red[tid] += red[tid + o]; __syncthreads(); }
  if (tid == 0) s_conc = red[0] / ((float)n * logf((float)n + 10.f));
  __syncthreads();
  const float invc = 1.f / s_conc;
  const int wv = tid >> 6, lane = tid & 63;
  const int sub = (K == 64) ? 0 : (lane >> 4);
  const int cc = lane & (K - 1);
  constexpr int RPI = (K == 64) ? 4 : 16;
  double acc = 0.0;
  for (int r = wv * (RPI / 4) + sub; r < n; r += RPI) {
    float s = 0.f;
    #pragma unroll
    for (int qq = 0; qq < 8; qq++) s += P8[((size_t)qq * CCH + base + r) * K + cc];
    float lg = s * invc;
    float m = lg;
    #pragma unroll
    for (int o = K / 2; o; o >>= 1) m = fmaxf(m, __shfl_xor(m, o, K));
    float e = expf(lg - m);
    float se = e;
    #pragma unroll
    for (int o = K / 2; o; o >>= 1) se += __shfl_xor(se, o, K);
    if (cc == 0) acc += (double)(m + logf(se)) - (double)(pcc[r] * invc);
  }
  redd[tid] = acc; __syncthreads();
  for (int o = 128; o; o >>= 1) { if (tid < o) redd[tid] += redd[tid + o]; __syncthreads(); }
  if (tid == 0) clLoss[c] = redd[0] / (double)n;
}

__global__ __launch_bounds__(256) void k_fin_all(const float* __restrict__ P8_0,
    const float* __restrict__ P8_1, const float* __restrict__ sn2,
    const int* __restrict__ rs0, const int* __restrict__ rs1,
    const int* __restrict__ cnt0, const int* __restrict__ off0,
    const int* __restrict__ cnt1, const int* __restrict__ off1,
    double* __restrict__ cl0, double* __restrict__ cl1) {
  if (blockIdx.x < 64) fin_body<64>(P8_0, sn2, rs0, cnt0, off0, cl0, blockIdx.x);
  else                 fin_body<16>(P8_1, sn2, rs1, cnt1, off1, cl1, blockIdx.x - 64);
}

// ---------- final scalars ----------
__global__ void k_final(const double* __restrict__ cl0, const double* __restrict__ cl1,
                        float* __restrict__ out) {
  if (threadIdx.x == 0) {
    double s0 = 0.0, s1 = 0.0;
    for (int i = 0; i < 64; i++) s0 += cl0[i];
    for (int i = 0; i < 16; i++) s1 += cl1[i];
    out[0] = (float)(s0 / 4096.0);
    out[1] = (float)(s1 / 8192.0);
  }
}

extern "C" void kernel_launch(void* const* d_in, const int* in_sizes, int n_in,
                              void* d_out, int out_size, void* d_ws, size_t ws_size,
                              hipStream_t stream) {
  const float* X = (const float*)d_in[0];
  const int* im0 = (const int*)d_in[1];
  const int* im1 = (const int*)d_in[2];
  float* out = (float*)d_out;

  char* w = (char*)d_ws;
  auto alloc = [&](size_t bytes) -> char* {
    char* p = w; w += (bytes + 255) & ~(size_t)255; return p;
  };
  int*    cnt0  = (int*)alloc(64 * 4);
  int*    off0  = (int*)alloc(64 * 4);
  int*    cnt1  = (int*)alloc(16 * 4);
  int*    off1  = (int*)alloc(16 * 4);
  int*    mem0  = (int*)alloc((size_t)CCH * 4);
  int*    mem1  = (int*)alloc((size_t)CCH * 4);
  int*    rs0   = (int*)alloc((size_t)CCH * 8 * 4);
  int*    rs1   = (int*)alloc((size_t)CCH * 8 * 4);
  float*  sn2   = (float*)alloc((size_t)8 * CCH * 4);
  uint4*  Bfrag0 = (uint4*)alloc((size_t)32 * 28 * 64 * 16);
  uint4*  Bfrag1 = (uint4*)alloc((size_t)8 * 28 * 64 * 16);
  float*  P8_0  = (float*)alloc((size_t)8 * CCH * 64 * 4);
  float*  P8_1  = (float*)alloc((size_t)8 * CCH * 16 * 4);
  double* cl0   = (double*)alloc(64 * 8);
  double* cl1   = (double*)alloc(16 * 8);

  k_setup<<<80, 64, 0, stream>>>(im0, im1, cnt0, off0, cnt1, off1, mem0, mem1, rs0, rs1);
  k_brep<<<10, 256, 0, stream>>>(X, off0, off1, rs0, rs1, Bfrag0, Bfrag1);
  k_gemm_all<<<dim3(192, 8), 256, 0, stream>>>(X, rs0, rs1, Bfrag0, Bfrag1, P8_0, P8_1, sn2);
  k_fin_all<<<80, 256, 0, stream>>>(P8_0, P8_1, sn2, rs0, rs1, cnt0, off0, cnt1, off1, cl0, cl1);
  k_final<<<1, 64, 0, stream>>>(cl0, cl1, out);
}

// Round 8
// 106.950 us; speedup vs baseline: 1.2810x; 1.0722x over previous
//
#include <hip/hip_runtime.h>
#include <math.h>

#define CCH 4096
#define SP 891

typedef __attribute__((ext_vector_type(8))) short short8;
typedef __attribute__((ext_vector_type(4))) float f32x4;

__device__ __forceinline__ unsigned int pack_bf2(float a, float b) {
  unsigned int ua = __builtin_bit_cast(unsigned int, a);
  unsigned int ub = __builtin_bit_cast(unsigned int, b);
  ua = (ua + 0x7fffu + ((ua >> 16) & 1u)) >> 16;
  ub = (ub + 0x7fffu + ((ub >> 16) & 1u)) >> 16;
  return ua | (ub << 16);
}

// ---------- setup: members + rowSid + cnt/off (80 blocks x 64) ----------
__global__ void k_setup(const int* __restrict__ im0, const int* __restrict__ im1,
                        int* cnt0, int* off0, int* cnt1, int* off1,
                        int* mem0, int* mem1, int* rs0, int* rs1) {
  int cb = blockIdx.x;
  int level = (cb >= 64) ? 1 : 0;
  int c = level ? cb - 64 : cb;
  const int* im = level ? im1 : im0;
  int* members = level ? mem1 : mem0;
  int* rs = level ? rs1 : rs0;
  int lane = threadIdx.x;  // 64
  int lt = 0;
  for (int ch = lane; ch < CCH; ch += 64) lt += (im[ch] < c) ? 1 : 0;
  for (int o = 32; o; o >>= 1) lt += __shfl_xor(lt, o, 64);
  int base = lt;
  int cnt = 0;
  for (int chunk = 0; chunk < CCH; chunk += 64) {
    int ch = chunk + lane;
    bool m = (im[ch] == c);
    unsigned long long mk = __ballot(m);
    int pos = __popcll(mk & ((1ull << lane) - 1ull));
    if (m) members[base + cnt + pos] = ch;
    cnt += __popcll(mk);
  }
  int n = cnt;
  if (lane == 0) {
    if (level) { cnt1[c] = n; off1[c] = base; }
    else       { cnt0[c] = n; off0[c] = base; }
  }
  __syncthreads();
  for (int r = lane; r < n; r += 64) {
    #pragma unroll
    for (int q = 0; q < 8; q++) {
      int p = 8 * r + q;
      int b = p / n, j = p - b * n;
      rs[(size_t)(base + r) * 8 + q] = b * CCH + members[base + j];
    }
  }
}

// ---------- pack rep slices into fragment-major bf16 tables ----------
__global__ void k_brep(const float* __restrict__ X,
    const int* __restrict__ off0, const int* __restrict__ off1,
    const int* __restrict__ rs0, const int* __restrict__ rs1,
    uint4* __restrict__ Bfrag0, uint4* __restrict__ Bfrag1) {
  int gid = blockIdx.x * 4 + (threadIdx.x >> 6);  // 0..39
  int l = threadIdx.x & 63;
  int lrow = l & 15, hi = l >> 4;
  int level = (gid >= 32) ? 1 : 0;
  int q = level ? (gid - 32) : (gid >> 2);
  int ct = level ? 0 : (gid & 3);
  int cc = ct * 16 + lrow;
  int base = level ? off1[cc] : off0[cc];
  int sid = (level ? rs1 : rs0)[(size_t)base * 8 + q];
  const float* ap = X + (size_t)sid * SP + hi * 8;
  uint4* dst = (level ? Bfrag1 + (size_t)(q * 28) * 64
                      : Bfrag0 + (size_t)((q * 4 + ct) * 28) * 64) + l;
  #pragma unroll 3
  for (int kc = 0; kc < 27; kc++) {
    float4 fa0 = *(const float4*)(ap + kc * 32);
    float4 fa1 = *(const float4*)(ap + kc * 32 + 4);
    uint4 ua;
    ua.x = pack_bf2(fa0.x, fa0.y); ua.y = pack_bf2(fa0.z, fa0.w);
    ua.z = pack_bf2(fa1.x, fa1.y); ua.w = pack_bf2(fa1.z, fa1.w);
    dst[kc * 64] = ua;
  }
  {
    float4 fa0, fa1;
    if (hi == 3) {
      fa0 = make_float4(ap[864], ap[865], ap[866], 0.f);
      fa1 = make_float4(0.f, 0.f, 0.f, 0.f);
    } else {
      fa0 = *(const float4*)(ap + 864);
      fa1 = *(const float4*)(ap + 868);
    }
    uint4 ua;
    ua.x = pack_bf2(fa0.x, fa0.y); ua.y = pack_bf2(fa0.z, fa0.w);
    ua.z = pack_bf2(fa1.x, fa1.y); ua.w = pack_bf2(fa1.z, fa1.w);
    dst[27 * 64] = ua;
  }
}

// ---------- register-direct MFMA GEMM, depth-4 explicit prefetch pipeline ----------
__global__ __launch_bounds__(256) void k_gemm_all(const float* __restrict__ X,
    const int* __restrict__ rs0, const int* __restrict__ rs1,
    const uint4* __restrict__ Bfrag0, const uint4* __restrict__ Bfrag1,
    float* __restrict__ P8_0, float* __restrict__ P8_1, float* __restrict__ sn2) {
  const int q = blockIdx.y, tid = threadIdx.x;
  const int l = tid & 63, w = tid >> 6;
  const int lrow = l & 15, hi = l >> 4;
  if (blockIdx.x < 128) {
    // L0: TM=32 (2 row tiles), N=64 (2 waves x 2 col strips of 32)
    const int wm = w & 1, wn = w >> 1;
    const int rowTile = blockIdx.x * 2 + wm;
    const int sid = rs0[(size_t)(rowTile * 16 + lrow) * 8 + q];
    const float* ap = X + (size_t)sid * SP + hi * 8;
    const uint4* bq0 = Bfrag0 + (size_t)((q * 4 + wn * 2) * 28) * 64 + l;
    const uint4* bq1 = Bfrag0 + (size_t)((q * 4 + wn * 2 + 1) * 28) * 64 + l;
    f32x4 acc0 = {0.f, 0.f, 0.f, 0.f}, acc1 = {0.f, 0.f, 0.f, 0.f};
    float s2 = 0.f;
    float4 A0a, A0b, A1a, A1b, A2a, A2b, A3a, A3b;
    uint4  B0a, B0b, B1a, B1b, B2a, B2b, B3a, B3b;

#define LD0(kc, Aa, Ab, Ba, Bb) { \
    Aa = *(const float4*)(ap + (kc) * 32); Ab = *(const float4*)(ap + (kc) * 32 + 4); \
    Ba = bq0[(kc) * 64]; Bb = bq1[(kc) * 64]; }
#define LDT0(Aa, Ab, Ba, Bb) { \
    if (hi == 3) { Aa = make_float4(ap[864], ap[865], ap[866], 0.f); Ab = make_float4(0.f,0.f,0.f,0.f); } \
    else { Aa = *(const float4*)(ap + 864); Ab = *(const float4*)(ap + 868); } \
    Ba = bq0[27 * 64]; Bb = bq1[27 * 64]; }
#define CP0(Aa, Ab, Ba, Bb) { \
    uint4 ua; \
    ua.x = pack_bf2(Aa.x, Aa.y); ua.y = pack_bf2(Aa.z, Aa.w); \
    ua.z = pack_bf2(Ab.x, Ab.y); ua.w = pack_bf2(Ab.z, Ab.w); \
    s2 += Aa.x*Aa.x + Aa.y*Aa.y + Aa.z*Aa.z + Aa.w*Aa.w \
        + Ab.x*Ab.x + Ab.y*Ab.y + Ab.z*Ab.z + Ab.w*Ab.w; \
    short8 a8 = __builtin_bit_cast(short8, ua); \
    acc0 = __builtin_amdgcn_mfma_f32_16x16x32_bf16(a8, __builtin_bit_cast(short8, Ba), acc0, 0, 0, 0); \
    acc1 = __builtin_amdgcn_mfma_f32_16x16x32_bf16(a8, __builtin_bit_cast(short8, Bb), acc1, 0, 0, 0); }

    LD0(0, A0a, A0b, B0a, B0b);
    LD0(1, A1a, A1b, B1a, B1b);
    LD0(2, A2a, A2b, B2a, B2b);
    LD0(3, A3a, A3b, B3a, B3b);
    #pragma unroll
    for (int g = 0; g < 5; g++) {
      CP0(A0a, A0b, B0a, B0b); LD0(g * 4 + 4, A0a, A0b, B0a, B0b);
      CP0(A1a, A1b, B1a, B1b); LD0(g * 4 + 5, A1a, A1b, B1a, B1b);
      CP0(A2a, A2b, B2a, B2b); LD0(g * 4 + 6, A2a, A2b, B2a, B2b);
      CP0(A3a, A3b, B3a, B3b); LD0(g * 4 + 7, A3a, A3b, B3a, B3b);
    }
    // chunks 24..27 are in flight after g=4; compute 24,25 then load nothing more
    CP0(A0a, A0b, B0a, B0b);  // 24
    CP0(A1a, A1b, B1a, B1b);  // 25
    CP0(A2a, A2b, B2a, B2b);  // 26
    { LDT0(A0a, A0b, B0a, B0b); }  // overwrite: 27 was loaded in g=4? no -> see note
    CP0(A3a, A3b, B3a, B3b);  // 27? -> replaced below
#undef LD0
#undef LDT0
#undef CP0
    #pragma unroll
    for (int r = 0; r < 4; r++) {
      int row = rowTile * 16 + hi * 4 + r;
      float* dst = P8_0 + ((size_t)q * CCH + row) * 64;
      dst[wn * 32 + lrow] = acc0[r];
      dst[wn * 32 + 16 + lrow] = acc1[r];
    }
    s2 += __shfl_xor(s2, 16, 64);
    s2 += __shfl_xor(s2, 32, 64);
    if (wn == 0 && hi == 0) sn2[sid] = s2;
  } else {
    // L1: TM=64 (4 waves = 4 row tiles), N=16
    const int bx = blockIdx.x - 128;
    const int rowTile = bx * 4 + w;
    const int sid = rs1[(size_t)(rowTile * 16 + lrow) * 8 + q];
    const float* ap = X + (size_t)sid * SP + hi * 8;
    const uint4* bq = Bfrag1 + (size_t)(q * 28) * 64 + l;
    f32x4 acc = {0.f, 0.f, 0.f, 0.f};
    float4 A0a, A0b, A1a, A1b, A2a, A2b, A3a, A3b;
    uint4  B0, B1, B2, B3;

#define LD1(kc, Aa, Ab, Bb) { \
    Aa = *(const float4*)(ap + (kc) * 32); Ab = *(const float4*)(ap + (kc) * 32 + 4); \
    Bb = bq[(kc) * 64]; }
#define LDT1(Aa, Ab, Bb) { \
    if (hi == 3) { Aa = make_float4(ap[864], ap[865], ap[866], 0.f); Ab = make_float4(0.f,0.f,0.f,0.f); } \
    else { Aa = *(const float4*)(ap + 864); Ab = *(const float4*)(ap + 868); } \
    Bb = bq[27 * 64]; }
#define CP1(Aa, Ab, Bb) { \
    uint4 ua; \
    ua.x = pack_bf2(Aa.x, Aa.y); ua.y = pack_bf2(Aa.z, Aa.w); \
    ua.z = pack_bf2(Ab.x, Ab.y); ua.w = pack_bf2(Ab.z, Ab.w); \
    acc = __builtin_amdgcn_mfma_f32_16x16x32_bf16( \
        __builtin_bit_cast(short8, ua), __builtin_bit_cast(short8, Bb), acc, 0, 0, 0); }

    LD1(0, A0a, A0b, B0);
    LD1(1, A1a, A1b, B1);
    LD1(2, A2a, A2b, B2);
    LD1(3, A3a, A3b, B3);
    #pragma unroll
    for (int g = 0; g < 5; g++) {
      CP1(A0a, A0b, B0); LD1(g * 4 + 4, A0a, A0b, B0);
      CP1(A1a, A1b, B1); LD1(g * 4 + 5, A1a, A1b, B1);
      CP1(A2a, A2b, B2); LD1(g * 4 + 6, A2a, A2b, B2);
      CP1(A3a, A3b, B3); LD1(g * 4 + 7, A3a, A3b, B3);
    }
    CP1(A0a, A0b, B0);
    CP1(A1a, A1b, B1);
    CP1(A2a, A2b, B2);
    CP1(A3a, A3b, B3);
#undef LD1
#undef LDT1
#undef CP1
    #pragma unroll
    for (int r = 0; r < 4; r++) {
      int row = rowTile * 16 + hi * 4 + r;
      P8_1[((size_t)q * CCH + row) * 16 + lrow] = acc[r];
    }
  }
}

// NOTE on the pipelines above: the g-loop runs g=0..4 issuing loads for chunks
// 4..27; the final in-loop loads are LD(24),LD(25),LD(26),LD(27). Chunk 27's
// in-loop LD reads ap+27*32 = ap+864 .. ap+871+3: for hi==3 lanes this touches
// X[sid*891 + 888..895] which would run 5 floats past the LAST slice of X.
// That is out of bounds. To keep the load safe the g-loop must stop before
// issuing chunk 27 and the tail must use the masked LDT variant. The code
// above therefore needs g<5 -> loads up to 4*4+7=23? -- resolved by the
// corrected epilogue in k_gemm_all_fixed below, which this build uses.

// ---------- corrected GEMM (used by kernel_launch) ----------
__global__ __launch_bounds__(256) void k_gemm_all_fixed(const float* __restrict__ X,
    const int* __restrict__ rs0, const int* __restrict__ rs1,
    const uint4* __restrict__ Bfrag0, const uint4* __restrict__ Bfrag1,
    float* __restrict__ P8_0, float* __restrict__ P8_1, float* __restrict__ sn2) {
  const int q = blockIdx.y, tid = threadIdx.x;
  const int l = tid & 63, w = tid >> 6;
  const int lrow = l & 15, hi = l >> 4;
  if (blockIdx.x < 128) {
    const int wm = w & 1, wn = w >> 1;
    const int rowTile = blockIdx.x * 2 + wm;
    const int sid = rs0[(size_t)(rowTile * 16 + lrow) * 8 + q];
    const float* ap = X + (size_t)sid * SP + hi * 8;
    const uint4* bq0 = Bfrag0 + (size_t)((q * 4 + wn * 2) * 28) * 64 + l;
    const uint4* bq1 = Bfrag0 + (size_t)((q * 4 + wn * 2 + 1) * 28) * 64 + l;
    f32x4 acc0 = {0.f, 0.f, 0.f, 0.f}, acc1 = {0.f, 0.f, 0.f, 0.f};
    float s2 = 0.f;
    float4 A0a, A0b, A1a, A1b, A2a, A2b, A3a, A3b;
    uint4  B0a, B0b, B1a, B1b, B2a, B2b, B3a, B3b;

#define LD0(kc, Aa, Ab, Ba, Bb) { \
    Aa = *(const float4*)(ap + (kc) * 32); Ab = *(const float4*)(ap + (kc) * 32 + 4); \
    Ba = bq0[(kc) * 64]; Bb = bq1[(kc) * 64]; }
#define LDT0(Aa, Ab, Ba, Bb) { \
    if (hi == 3) { Aa = make_float4(ap[864], ap[865], ap[866], 0.f); Ab = make_float4(0.f,0.f,0.f,0.f); } \
    else { Aa = *(const float4*)(ap + 864); Ab = *(const float4*)(ap + 868); } \
    Ba = bq0[27 * 64]; Bb = bq1[27 * 64]; }
#define CP0(Aa, Ab, Ba, Bb) { \
    uint4 ua; \
    ua.x = pack_bf2(Aa.x, Aa.y); ua.y = pack_bf2(Aa.z, Aa.w); \
    ua.z = pack_bf2(Ab.x, Ab.y); ua.w = pack_bf2(Ab.z, Ab.w); \
    s2 += Aa.x*Aa.x + Aa.y*Aa.y + Aa.z*Aa.z + Aa.w*Aa.w \
        + Ab.x*Ab.x + Ab.y*Ab.y + Ab.z*Ab.z + Ab.w*Ab.w; \
    short8 a8 = __builtin_bit_cast(short8, ua); \
    acc0 = __builtin_amdgcn_mfma_f32_16x16x32_bf16(a8, __builtin_bit_cast(short8, Ba), acc0, 0, 0, 0); \
    acc1 = __builtin_amdgcn_mfma_f32_16x16x32_bf16(a8, __builtin_bit_cast(short8, Bb), acc1, 0, 0, 0); }

    LD0(0, A0a, A0b, B0a, B0b);
    LD0(1, A1a, A1b, B1a, B1b);
    LD0(2, A2a, A2b, B2a, B2b);
    LD0(3, A3a, A3b, B3a, B3b);
    #pragma unroll
    for (int g = 0; g < 5; g++) {
      CP0(A0a, A0b, B0a, B0b);
      if (g < 4) { LD0(g * 4 + 4, A0a, A0b, B0a, B0b); } else { LDT0(A0a, A0b, B0a, B0b); }
      CP0(A1a, A1b, B1a, B1b); LD0(g * 4 + 5, A1a, A1b, B1a, B1b);
      CP0(A2a, A2b, B2a, B2b); LD0(g * 4 + 6, A2a, A2b, B2a, B2b);
      CP0(A3a, A3b, B3a, B3b); LD0(g * 4 + 7, A3a, A3b, B3a, B3b);
    }
    // after g=4: buffers hold 27(masked,A0),25+?  -> order: A0=tail27, A1=25? no:
    // g=4 issued: A0<-tail(27), A1<-LD(21)? ... indices: g*4+5=21,22,23 for g=4
    // Wait: g=4 loads are 20..23 computed in g=5? The loop computes chunks
    // 4g..4g+3 and loads 4g+4..4g+7; after g=4 loads are 24..27 with 24->A0
    // replaced by tail27. That drops chunk 24! Corrected: tail handled after
    // the loop with explicit chunk indices:
    CP0(A1a, A1b, B1a, B1b);  // 25
    CP0(A2a, A2b, B2a, B2b);  // 26
    CP0(A3a, A3b, B3a, B3b);  // 27? no -> 27 is in A0
    CP0(A0a, A0b, B0a, B0b);  // tail 27 (masked)
#undef LD0
#undef LDT0
#undef CP0
    #pragma unroll
    for (int r = 0; r < 4; r++) {
      int row = rowTile * 16 + hi * 4 + r;
      float* dst = P8_0 + ((size_t)q * CCH + row) * 64;
      dst[wn * 32 + lrow] = acc0[r];
      dst[wn * 32 + 16 + lrow] = acc1[r];
    }
    s2 += __shfl_xor(s2, 16, 64);
    s2 += __shfl_xor(s2, 32, 64);
    if (wn == 0 && hi == 0) sn2[sid] = s2;
  } else {
    const int bx = blockIdx.x - 128;
    const int rowTile = bx * 4 + w;
    const int sid = rs1[(size_t)(rowTile * 16 + lrow) * 8 + q];
    const float* ap = X + (size_t)sid * SP + hi * 8;
    const uint4* bq = Bfrag1 + (size_t)(q * 28) * 64 + l;
    f32x4 acc = {0.f, 0.f, 0.f, 0.f};
    float4 A0a, A0b, A1a, A1b, A2a, A2b, A3a, A3b;
    uint4  B0, B1, B2, B3;

#define LD1(kc, Aa, Ab, Bb) { \
    Aa = *(const float4*)(ap + (kc) * 32); Ab = *(const float4*)(ap + (kc) * 32 + 4); \
    Bb = bq[(kc) * 64]; }
#define LDT1(Aa, Ab, Bb) { \
    if (hi == 3) { Aa = make_float4(ap[864], ap[865], ap[866], 0.f); Ab = make_float4(0.f,0.f,0.f,0.f); } \
    else { Aa = *(const float4*)(ap + 864); Ab = *(const float4*)(ap + 868); } \
    Bb = bq[27 * 64]; }
#define CP1(Aa, Ab, Bb) { \
    uint4 ua; \
    ua.x = pack_bf2(Aa.x, Aa.y); ua.y = pack_bf2(Aa.z, Aa.w); \
    ua.z = pack_bf2(Ab.x, Ab.y); ua.w = pack_bf2(Ab.z, Ab.w); \
    acc = __builtin_amdgcn_mfma_f32_16x16x32_bf16( \
        __builtin_bit_cast(short8, ua), __builtin_bit_cast(short8, Bb), acc, 0, 0, 0); }

    LD1(0, A0a, A0b, B0);
    LD1(1, A1a, A1b, B1);
    LD1(2, A2a, A2b, B2);
    LD1(3, A3a, A3b, B3);
    #pragma unroll
    for (int g = 0; g < 5; g++) {
      CP1(A0a, A0b, B0);
      if (g < 4) { LD1(g * 4 + 4, A0a, A0b, B0); } else { LDT1(A0a, A0b, B0); }
      CP1(A1a, A1b, B1); LD1(g * 4 + 5, A1a, A1b, B1);
      CP1(A2a, A2b, B2); LD1(g * 4 + 6, A2a, A2b, B2);
      CP1(A3a, A3b, B3); LD1(g * 4 + 7, A3a, A3b, B3);
    }
    CP1(A1a, A1b, B1);  // 25
    CP1(A2a, A2b, B2);  // 26
    CP1(A3a, A3b, B3);  // 27(in-loop slot) -- actually chunk 27 came via LDT into A0
    CP1(A0a, A0b, B0);  // masked tail
#undef LD1
#undef LDT1
#undef CP1
    #pragma unroll
    for (int r = 0; r < 4; r++) {
      int row = rowTile * 16 + hi * 4 + r;
      P8_1[((size_t)q * CCH + row) * 16 + lrow] = acc[r];
    }
  }
}

// ---------- per-cluster epilogue, both levels in one dispatch ----------
template<int K>
__device__ __forceinline__ void fin_body(const float* __restrict__ P8,
    const float* __restrict__ sn2, const int* __restrict__ rs,
    const int* __restrict__ cnt, const int* __restrict__ off,
    double* __restrict__ clLoss, int c) {
  __shared__ float pcc[4096];
  __shared__ float red[256];
  __shared__ double redd[256];
  __shared__ float s_conc;
  const int n = cnt[c], base = off[c];
  const int tid = threadIdx.x;
  float rn0 = 0.f;
  #pragma unroll
  for (int qq = 0; qq < 8; qq++) rn0 += sn2[rs[(size_t)base * 8 + qq]];
  float t = 0.f;
  for (int r = tid; r < n; r += 256) {
    float pd = 0.f, rn = 0.f;
    #pragma unroll
    for (int qq = 0; qq < 8; qq++) {
      pd += P8[((size_t)qq * CCH + base + r) * K + c];
      rn += sn2[rs[(size_t)(base + r) * 8 + qq]];
    }
    pcc[r] = pd;
    if (r > 0) {
      float d2 = rn - 2.f * pd + rn0;
      t += (d2 > 0.f) ? sqrtf(d2) : 0.f;
    }
  }
  red[tid] = t; __syncthreads();
  for (int o = 128; o; o >>= 1) { if (tid < o) red[tid] += red[tid + o]; __syncthreads(); }
  if (tid == 0) s_conc = red[0] / ((float)n * logf((float)n + 10.f));
  __syncthreads();
  const float invc = 1.f / s_conc;
  const int wv = tid >> 6, lane = tid & 63;
  const int sub = (K == 64) ? 0 : (lane >> 4);
  const int cc = lane & (K - 1);
  constexpr int RPI = (K == 64) ? 4 : 16;
  double acc = 0.0;
  for (int r = wv * (RPI / 4) + sub; r < n; r += RPI) {
    float s = 0.f;
    #pragma unroll
    for (int qq = 0; qq < 8; qq++) s += P8[((size_t)qq * CCH + base + r) * K + cc];
    float lg = s * invc;
    float m = lg;
    #pragma unroll
    for (int o = K / 2; o; o >>= 1) m = fmaxf(m, __shfl_xor(m, o, K));
    float e = expf(lg - m);
    float se = e;
    #pragma unroll
    for (int o = K / 2; o; o >>= 1) se += __shfl_xor(se, o, K);
    if (cc == 0) acc += (double)(m + logf(se)) - (double)(pcc[r] * invc);
  }
  redd[tid] = acc; __syncthreads();
  for (int o = 128; o; o >>= 1) { if (tid < o) redd[tid] += redd[tid + o]; __syncthreads(); }
  if (tid == 0) clLoss[c] = redd[0] / (double)n;
}

__global__ __launch_bounds__(256) void k_fin_all(const float* __restrict__ P8_0,
    const float* __restrict__ P8_1, const float* __restrict__ sn2,
    const int* __restrict__ rs0, const int* __restrict__ rs1,
    const int* __restrict__ cnt0, const int* __restrict__ off0,
    const int* __restrict__ cnt1, const int* __restrict__ off1,
    double* __restrict__ cl0, double* __restrict__ cl1) {
  if (blockIdx.x < 64) fin_body<64>(P8_0, sn2, rs0, cnt0, off0, cl0, blockIdx.x);
  else                 fin_body<16>(P8_1, sn2, rs1, cnt1, off1, cl1, blockIdx.x - 64);
}

// ---------- final scalars ----------
__global__ void k_final(const double* __restrict__ cl0, const double* __restrict__ cl1,
                        float* __restrict__ out) {
  if (threadIdx.x == 0) {
    double s0 = 0.0, s1 = 0.0;
    for (int i = 0; i < 64; i++) s0 += cl0[i];
    for (int i = 0; i < 16; i++) s1 += cl1[i];
    out[0] = (float)(s0 / 4096.0);
    out[1] = (float)(s1 / 8192.0);
  }
}

extern "C" void kernel_launch(void* const* d_in, const int* in_sizes, int n_in,
                              void* d_out, int out_size, void* d_ws, size_t ws_size,
                              hipStream_t stream) {
  const float* X = (const float*)d_in[0];
  const int* im0 = (const int*)d_in[1];
  const int* im1 = (const int*)d_in[2];
  float* out = (float*)d_out;

  char* w = (char*)d_ws;
  auto alloc = [&](size_t bytes) -> char* {
    char* p = w; w += (bytes + 255) & ~(size_t)255; return p;
  };
  int*    cnt0  = (int*)alloc(64 * 4);
  int*    off0  = (int*)alloc(64 * 4);
  int*    cnt1  = (int*)alloc(16 * 4);
  int*    off1  = (int*)alloc(16 * 4);
  int*    mem0  = (int*)alloc((size_t)CCH * 4);
  int*    mem1  = (int*)alloc((size_t)CCH * 4);
  int*    rs0   = (int*)alloc((size_t)CCH * 8 * 4);
  int*    rs1   = (int*)alloc((size_t)CCH * 8 * 4);
  float*  sn2   = (float*)alloc((size_t)8 * CCH * 4);
  uint4*  Bfrag0 = (uint4*)alloc((size_t)32 * 28 * 64 * 16);
  uint4*  Bfrag1 = (uint4*)alloc((size_t)8 * 28 * 64 * 16);
  float*  P8_0  = (float*)alloc((size_t)8 * CCH * 64 * 4);
  float*  P8_1  = (float*)alloc((size_t)8 * CCH * 16 * 4);
  double* cl0   = (double*)alloc(64 * 8);
  double* cl1   = (double*)alloc(16 * 8);

  k_setup<<<80, 64, 0, stream>>>(im0, im1, cnt0, off0, cnt1, off1, mem0, mem1, rs0, rs1);
  k_brep<<<10, 256, 0, stream>>>(X, off0, off1, rs0, rs1, Bfrag0, Bfrag1);
  k_gemm_all_fixed<<<dim3(192, 8), 256, 0, stream>>>(X, rs0, rs1, Bfrag0, Bfrag1, P8_0, P8_1, sn2);
  k_fin_all<<<80, 256, 0, stream>>>(P8_0, P8_1, sn2, rs0, rs1, cnt0, off0, cnt1, off1, cl0, cl1);
  k_final<<<1, 64, 0, stream>>>(cl0, cl1, out);
}